// Round 1
// baseline (1212.658 us; speedup 1.0000x reference)
//
#include <hip/hip_runtime.h>
#include <math.h>

// Problem constants
#define SEQ 577
#define BB  64
#define DD  768
#define HH  12
#define KK  8
#define PP  576                 // SEQ-1 patches
#define ROWS (PP*BB)            // 36864 (p-major, b-minor: r = p*64 + b)
#define GAMMA_C 5.0f
#define EPS_C 1e-8f

// ---------------------------------------------------------------------------
// K0: per-batch cls-attn stats -> fg_mask, plus ||text_cls[b]||.
// One block per b. Double accumulation to track the (likely f64) numpy ref
// as closely as possible for the discontinuous fg comparison.
// ---------------------------------------------------------------------------
__global__ __launch_bounds__(768) void k0_attn_stats(
    const float* __restrict__ attn, const float* __restrict__ text,
    float* __restrict__ fg, float* __restrict__ tnorm)
{
    const int b = blockIdx.x;
    const int tid = threadIdx.x;
    __shared__ double red[768];

    // cls_attn[b, p] = mean over h of attn[b, h, 0, 1+p]
    double ca = 0.0;
    if (tid < PP) {
        const float* base = attn + (size_t)b * HH * SEQ * SEQ + 1 + tid;
        #pragma unroll
        for (int h = 0; h < HH; ++h) ca += (double)base[(size_t)h * SEQ * SEQ];
        ca *= (1.0 / 12.0);
    }
    red[tid] = (tid < PP) ? ca : 0.0;
    __syncthreads();
    for (int s = 512; s > 0; s >>= 1) {
        if (tid < s && tid + s < 768) red[tid] += red[tid + s];
        __syncthreads();
    }
    const double mu = red[0] / (double)PP;   // read before overwrite
    __syncthreads();
    const double dv = (tid < PP) ? (ca - mu) : 0.0;
    red[tid] = dv * dv;
    __syncthreads();
    for (int s = 512; s > 0; s >>= 1) {
        if (tid < s && tid + s < 768) red[tid] += red[tid + s];
        __syncthreads();
    }
    const double sigma = sqrt(red[0] / (double)(PP - 1));
    const double cutoff = mu + 1.5 * sigma;
    if (tid < PP) fg[tid * BB + b] = (ca > cutoff) ? 1.0f : 0.0f;
    __syncthreads();

    // ||text_cls[b]||
    double ts = 0.0;
    for (int i = tid; i < DD; i += 768) {
        double v = (double)text[(size_t)b * DD + i];
        ts += v * v;
    }
    red[tid] = ts;
    __syncthreads();
    for (int s = 512; s > 0; s >>= 1) {
        if (tid < s && tid + s < 768) red[tid] += red[tid + s];
        __syncthreads();
    }
    if (tid == 0) tnorm[b] = (float)sqrt(red[0]);
}

// ---------------------------------------------------------------------------
// K1: per-row (p,b) fused 10-way dot products: dot(x,text), ||x||^2, 8x dot(x,pc[k]).
// One wave per row; wave processes PW rows of the SAME b so text_cls and the
// pc slices live in registers (no repeated L1 traffic for the small operands).
// Lane l owns d = {l*4 + 256*j + 0..3 : j=0..2}, fully coalesced float4 loads.
// ---------------------------------------------------------------------------
#define PW 12
#define CHUNKS (PP / PW)        // 48
#define K1_BLOCKS (BB * CHUNKS / 4)  // 3072 waves / 4 waves-per-block = 768

__global__ __launch_bounds__(256) void k1_rowstats(
    const float* __restrict__ x, const float* __restrict__ text,
    const float* __restrict__ pc, const float* __restrict__ tnorm,
    float* __restrict__ anomaly, float* __restrict__ coeff)
{
    const int wave = (blockIdx.x << 2) | (threadIdx.x >> 6);
    const int lane = threadIdx.x & 63;
    const int b = wave & (BB - 1);
    const int chunk = wave >> 6;         // 0..47
    const int p0 = chunk * PW;

    const float4* x4 = (const float4*)x;
    const float4* t4 = (const float4*)text;
    const float4* p4 = (const float4*)pc;

    // pc slices in registers: 8k x 3j x float4 = 96 VGPR
    float4 pcr[KK][3];
    #pragma unroll
    for (int k = 0; k < KK; ++k)
        #pragma unroll
        for (int j = 0; j < 3; ++j)
            pcr[k][j] = p4[k * 192 + j * 64 + lane];
    float4 tr[3];
    #pragma unroll
    for (int j = 0; j < 3; ++j) tr[j] = t4[b * 192 + j * 64 + lane];
    const float tn = tnorm[b];

    for (int pi = 0; pi < PW; ++pi) {
        const int r = (p0 + pi) * BB + b;
        const float4* xrow = x4 + (size_t)(BB + r) * 192;  // x row (1+p, b)

        float acc[10];  // [0]=dot(text) [1]=sumsq [2..9]=coeff
        #pragma unroll
        for (int i = 0; i < 10; ++i) acc[i] = 0.0f;

        #pragma unroll
        for (int j = 0; j < 3; ++j) {
            const float4 xa = xrow[j * 64 + lane];
            acc[0] += xa.x * tr[j].x + xa.y * tr[j].y + xa.z * tr[j].z + xa.w * tr[j].w;
            acc[1] += xa.x * xa.x + xa.y * xa.y + xa.z * xa.z + xa.w * xa.w;
            #pragma unroll
            for (int k = 0; k < KK; ++k)
                acc[2 + k] += xa.x * pcr[k][j].x + xa.y * pcr[k][j].y
                            + xa.z * pcr[k][j].z + xa.w * pcr[k][j].w;
        }
        // 64-lane butterfly reduce, all 10 accumulators
        #pragma unroll
        for (int off = 32; off; off >>= 1)
            #pragma unroll
            for (int i = 0; i < 10; ++i)
                acc[i] += __shfl_xor(acc[i], off, 64);

        if (lane == 0) {
            const float nrm = sqrtf(acc[1]);
            const float ts = acc[0] / (fmaxf(nrm, EPS_C) * fmaxf(tn, EPS_C));
            const float an = nrm * (1.0f - fmaxf(ts, 0.0f));
            anomaly[r] = an;
            float4 c0 = {acc[2], acc[3], acc[4], acc[5]};
            float4 c1 = {acc[6], acc[7], acc[8], acc[9]};
            float4* c4 = (float4*)(coeff + (size_t)r * 8);
            c4[0] = c0;
            c4[1] = c1;
        }
    }
}

// ---------------------------------------------------------------------------
// K2: global background stats -> scalar gate threshold. Single block, double.
// var_bg computed via exact expansion SS - 2*mu*S + N*mu^2 (matches ref's
// two-pass formula including the max(n,1)/max(n-1,1) denominators).
// ---------------------------------------------------------------------------
__global__ __launch_bounds__(1024) void k2_threshold(
    const float* __restrict__ fg, const float* __restrict__ an,
    float* __restrict__ thrOut)
{
    const int tid = threadIdx.x;
    double n = 0.0, s = 0.0, ss = 0.0;
    float mx = -1e30f;
    for (int i = tid; i < ROWS; i += 1024) {
        const float a = an[i];
        mx = fmaxf(mx, a);
        if (fg[i] < 0.5f) {
            const double ad = (double)a;
            n += 1.0; s += ad; ss += ad * ad;
        }
    }
    #pragma unroll
    for (int off = 32; off; off >>= 1) {
        n += __shfl_xor(n, off, 64);
        s += __shfl_xor(s, off, 64);
        ss += __shfl_xor(ss, off, 64);
        mx = fmaxf(mx, __shfl_xor(mx, off, 64));
    }
    __shared__ double sn[16], sss[16], ssq[16];
    __shared__ float smx[16];
    const int w = tid >> 6;
    if ((tid & 63) == 0) { sn[w] = n; sss[w] = s; ssq[w] = ss; smx[w] = mx; }
    __syncthreads();
    if (tid == 0) {
        double N = 0, S = 0, SS = 0; float MX = -1e30f;
        for (int i = 0; i < 16; ++i) { N += sn[i]; S += sss[i]; SS += ssq[i]; MX = fmaxf(MX, smx[i]); }
        const double mu = S / fmax(N, 1.0);
        const double var = (SS - 2.0 * mu * S + N * mu * mu) / fmax(N - 1.0, 1.0);
        const double thr = mu + 3.0 * sqrt(fmax(var, 0.0));
        thrOut[0] = (N > 0.0) ? (float)thr : MX;
    }
}

// ---------------------------------------------------------------------------
// K3: out = g*x + (1-g)*proj, proj = coeff @ pc; plus cls-row passthrough.
// 16 rows per block; each thread owns a fixed float4 d-slice so its pc
// column slice (8 float4 = 32 VGPR) is loaded once and reused for all rows.
// ---------------------------------------------------------------------------
#define RPB 16
#define NROWBLK (ROWS / RPB)    // 2304
#define CLSBLK  (BB * DD / (192 * 4))  // 64 blocks for the cls copy

__global__ __launch_bounds__(192) void k3_output(
    const float* __restrict__ x, const float* __restrict__ pc,
    const float* __restrict__ fg, const float* __restrict__ anomaly,
    const float* __restrict__ coeff, const float* __restrict__ thrP,
    float* __restrict__ out)
{
    const int t = threadIdx.x;
    const float4* x4 = (const float4*)x;
    float4* o4 = (float4*)out;

    if (blockIdx.x >= NROWBLK) {   // cls token passthrough: rows 0..63 of x
        const int idx = (blockIdx.x - NROWBLK) * 192 + t;
        o4[idx] = x4[idx];
        return;
    }

    const float4* p4 = (const float4*)pc;
    float4 pcr[KK];
    #pragma unroll
    for (int k = 0; k < KK; ++k) pcr[k] = p4[k * 192 + t];
    const float thr = thrP[0];
    const float4* c4 = (const float4*)coeff;
    const int r0 = blockIdx.x * RPB;

    for (int i = 0; i < RPB; ++i) {
        const int r = r0 + i;
        const float an = anomaly[r];
        const float fgv = fg[r];
        const float sig = 1.0f / (1.0f + __expf(-GAMMA_C * (thr - an)));
        const float g = fgv + (1.0f - fgv) * sig;
        const float4 ca = c4[(size_t)r * 2];
        const float4 cb = c4[(size_t)r * 2 + 1];
        const float4 xa = x4[(size_t)(BB + r) * 192 + t];
        float4 proj, res;
        proj.x = ca.x * pcr[0].x + ca.y * pcr[1].x + ca.z * pcr[2].x + ca.w * pcr[3].x
               + cb.x * pcr[4].x + cb.y * pcr[5].x + cb.z * pcr[6].x + cb.w * pcr[7].x;
        proj.y = ca.x * pcr[0].y + ca.y * pcr[1].y + ca.z * pcr[2].y + ca.w * pcr[3].y
               + cb.x * pcr[4].y + cb.y * pcr[5].y + cb.z * pcr[6].y + cb.w * pcr[7].y;
        proj.z = ca.x * pcr[0].z + ca.y * pcr[1].z + ca.z * pcr[2].z + ca.w * pcr[3].z
               + cb.x * pcr[4].z + cb.y * pcr[5].z + cb.z * pcr[6].z + cb.w * pcr[7].z;
        proj.w = ca.x * pcr[0].w + ca.y * pcr[1].w + ca.z * pcr[2].w + ca.w * pcr[3].w
               + cb.x * pcr[4].w + cb.y * pcr[5].w + cb.z * pcr[6].w + cb.w * pcr[7].w;
        const float gi = 1.0f - g;
        res.x = g * xa.x + gi * proj.x;
        res.y = g * xa.y + gi * proj.y;
        res.z = g * xa.z + gi * proj.z;
        res.w = g * xa.w + gi * proj.w;
        o4[(size_t)(BB + r) * 192 + t] = res;
    }
}

// ---------------------------------------------------------------------------
extern "C" void kernel_launch(void* const* d_in, const int* in_sizes, int n_in,
                              void* d_out, int out_size, void* d_ws, size_t ws_size,
                              hipStream_t stream)
{
    const float* x    = (const float*)d_in[0];
    const float* attn = (const float*)d_in[1];
    const float* text = (const float*)d_in[2];
    const float* pc   = (const float*)d_in[3];
    float* out = (float*)d_out;

    // workspace layout (floats): fg[ROWS] | anomaly[ROWS] | tnorm[64] | thr[4] | coeff[ROWS*8]
    float* ws      = (float*)d_ws;
    float* fg      = ws;
    float* anomaly = fg + ROWS;
    float* tnorm   = anomaly + ROWS;
    float* thr     = tnorm + BB;
    float* coeff   = thr + 4;          // offset 73796 floats -> 16B aligned

    hipLaunchKernelGGL(k0_attn_stats, dim3(BB), dim3(768), 0, stream,
                       attn, text, fg, tnorm);
    hipLaunchKernelGGL(k1_rowstats, dim3(K1_BLOCKS), dim3(256), 0, stream,
                       x, text, pc, tnorm, anomaly, coeff);
    hipLaunchKernelGGL(k2_threshold, dim3(1), dim3(1024), 0, stream,
                       fg, anomaly, thr);
    hipLaunchKernelGGL(k3_output, dim3(NROWBLK + CLSBLK), dim3(192), 0, stream,
                       x, pc, fg, anomaly, coeff, thr, out);
}